// Round 1
// baseline (1060.761 us; speedup 1.0000x reference)
//
#include <hip/hip_runtime.h>
#include <hip/hip_bf16.h>

// Problem constants
#define BQ   8
#define NLQ  1024
#define NQ   2048
#define DQ   128

typedef __attribute__((ext_vector_type(4))) float f32x4;
typedef __attribute__((ext_vector_type(8))) short bf16x8;

__device__ __forceinline__ unsigned short bfbits(float f) {
  __hip_bfloat16 h = __float2bfloat16(f);
  return __builtin_bit_cast(unsigned short, h);
}
__device__ __forceinline__ float sigm(float x) { return 1.f / (1.f + expf(-x)); }

// async global->LDS, 16B per lane. LDS dest must be wave-uniform base (HW adds lane*16).
__device__ __forceinline__ void g2l16(const void* g, void* l) {
  __builtin_amdgcn_global_load_lds(
      (__attribute__((address_space(1))) void*)(uintptr_t)g,
      (__attribute__((address_space(3))) void*)(uint32_t)(uintptr_t)l,
      16, 0, 0);
}

// ---------------------------------------------------------------------------
// Generic bf16 MFMA GEMM: C(M x Ncols) = A(M x K, row-major; optionally split
// into two 128-wide buffers at k=ksplit) * BT(Ncols x K, row-major)^T
// Tile: 64 (M) x 128 (N), BK=64, 4 waves, each wave 32x64.
// EPI: 0=msgs(bf16 out), 1=z/r+rh, 2=ht+GRU update, 3=in-proj
// ---------------------------------------------------------------------------
template <int EPI>
__global__ __launch_bounds__(256) void gemm_bf16(
    const __hip_bfloat16* __restrict__ A0, const __hip_bfloat16* __restrict__ A1,
    const __hip_bfloat16* __restrict__ BT,
    int ldA, int ksplit, int ldBT, int K,
    size_t aBatchStride, size_t btBatchStride, int rowsPerBatch,
    const float* __restrict__ bias0, const float* __restrict__ bias1,
    float* __restrict__ hF, float* __restrict__ zF,
    __hip_bfloat16* __restrict__ bf0, __hip_bfloat16* __restrict__ bf1) {
  __shared__ __align__(16) __hip_bfloat16 As[64 * 64];
  __shared__ __align__(16) __hip_bfloat16 Bs[128 * 64];
  const int t = threadIdx.x;
  const int lane = t & 63;
  const int w = t >> 6;
  const int wr = w >> 1, wc = w & 1;
  const int bm = blockIdx.x, bn = blockIdx.y, bz = blockIdx.z;

  const __hip_bfloat16* aB0 = A0 + (size_t)bz * aBatchStride + (size_t)bm * 64 * ldA;
  const __hip_bfloat16* aB1 = A1 ? (A1 + (size_t)bm * 64 * ldA) : (const __hip_bfloat16*)0;
  const __hip_bfloat16* btB = BT + (size_t)bz * btBatchStride + (size_t)bn * 128 * ldBT;

  f32x4 acc[2][4] = {};

  const int srA = w * 16 + (lane >> 3);  // + q*8
  const int srB = w * 32 + (lane >> 3);  // + q*8
  const int slot = lane & 7;
  const int lr = lane & 15, lh = lane >> 4;

  for (int k0 = 0; k0 < K; k0 += 64) {
    const __hip_bfloat16* aSrc = (k0 < ksplit) ? aB0 : aB1;
    const int kl = (k0 < ksplit) ? k0 : (k0 - ksplit);
    __syncthreads();  // previous iteration's LDS reads done
#pragma unroll
    for (int q = 0; q < 2; ++q)
      g2l16(aSrc + (size_t)(srA + q * 8) * ldA + kl + slot * 8,
            (char*)As + w * 2048 + q * 1024);
#pragma unroll
    for (int q = 0; q < 4; ++q)
      g2l16(btB + (size_t)(srB + q * 8) * ldBT + k0 + slot * 8,
            (char*)Bs + w * 4096 + q * 1024);
    asm volatile("s_waitcnt vmcnt(0)" ::: "memory");
    __syncthreads();
#pragma unroll
    for (int kk = 0; kk < 64; kk += 32) {
      bf16x8 av[2], bv[4];
#pragma unroll
      for (int m = 0; m < 2; ++m)
        av[m] = *(const bf16x8*)&As[(wr * 32 + m * 16 + lr) * 64 + kk + lh * 8];
#pragma unroll
      for (int n = 0; n < 4; ++n)
        bv[n] = *(const bf16x8*)&Bs[(wc * 64 + n * 16 + lr) * 64 + kk + lh * 8];
#pragma unroll
      for (int m = 0; m < 2; ++m)
#pragma unroll
        for (int n = 0; n < 4; ++n)
          acc[m][n] = __builtin_amdgcn_mfma_f32_16x16x32_bf16(av[m], bv[n], acc[m][n], 0, 0, 0);
    }
  }

  // Epilogue. C/D layout: col = lane&15, row = (lane>>4)*4 + reg.
#pragma unroll
  for (int m = 0; m < 2; ++m) {
    const int row0 = bm * 64 + wr * 32 + m * 16 + lh * 4;
    const int gRow = bz * rowsPerBatch + row0;
#pragma unroll
    for (int n = 0; n < 4; ++n) {
      const int col = bn * 128 + wc * 64 + n * 16 + lr;
      f32x4 v = acc[m][n];
      if constexpr (EPI == 0) {  // msgs -> bf16
#pragma unroll
        for (int r = 0; r < 4; ++r)
          bf0[(size_t)(gRow + r) * DQ + col] = __float2bfloat16(v[r]);
      } else if constexpr (EPI == 1) {  // z (cols<128) / r -> r*h (cols>=128)
        if (col < 128) {               // block-uniform branch (bn==0)
          const float bb = bias0[col];
#pragma unroll
          for (int r = 0; r < 4; ++r)
            zF[(size_t)(gRow + r) * DQ + col] = sigm(v[r] + bb);
        } else {
          const int c = col - 128;
          const float bb = bias1[c];
#pragma unroll
          for (int r = 0; r < 4; ++r) {
            size_t idx = (size_t)(gRow + r) * DQ + c;
            float rr = sigm(v[r] + bb);
            bf0[idx] = __float2bfloat16(rr * hF[idx]);
          }
        }
      } else {  // EPI 2 (ht + GRU update) and EPI 3 (in-proj)
        const float bb = bias0[col];
        ushort4 us;
        unsigned short* up = (unsigned short*)&us;
#pragma unroll
        for (int r = 0; r < 4; ++r) {
          size_t idx = (size_t)(gRow + r) * DQ + col;
          float hn;
          if constexpr (EPI == 2) {
            float tv = tanhf(v[r] + bb);
            float zv = zF[idx];
            float hv = hF[idx];
            hn = zv * hv + (1.f - zv) * tv;
          } else {
            hn = v[r] + bb;
          }
          hF[idx] = hn;
          bf0[idx] = __float2bfloat16(hn);
          up[r] = bfbits(hn);
        }
        // transposed bf16 write: hT[b][d][n], 4 consecutive n -> one 8B store
        const int bb_ = gRow >> 11;
        const int nl = gRow & 2047;
        *(ushort4*)((char*)bf1 + ((size_t)bb_ * (DQ * NQ) + (size_t)col * NQ + nl) * 2) = us;
      }
    }
  }
}

// ---------------------------------------------------------------------------
__global__ void cvt_adj(const float4* __restrict__ in, ushort4* __restrict__ out, int n4) {
  int stride = gridDim.x * blockDim.x;
  for (int i = blockIdx.x * blockDim.x + threadIdx.x; i < n4; i += stride) {
    float4 v = in[i];
    ushort4 o;
    o.x = bfbits(v.x); o.y = bfbits(v.y); o.z = bfbits(v.z); o.w = bfbits(v.w);
    out[i] = o;
  }
}

// Pack weights to bf16, transposed to N x K row-major.
__global__ void pack_weights(const float* __restrict__ ugW, const float* __restrict__ rgW,
                             const float* __restrict__ htW, const float* __restrict__ inW,
                             __hip_bfloat16* __restrict__ wzrT, __hip_bfloat16* __restrict__ htT,
                             __hip_bfloat16* __restrict__ inT) {
  int idx = blockIdx.x * 256 + threadIdx.x;
  if (idx < 5 * 256 * 256) {  // wzrT[i][n][k], n<128 -> ug, else rg
    int i = idx >> 16, r = idx & 65535, nn = r >> 8, k = r & 255;
    float v = (nn < 128) ? ugW[(i * 256 + k) * 128 + nn] : rgW[(i * 256 + k) * 128 + nn - 128];
    wzrT[idx] = __float2bfloat16(v);
    return;
  }
  int j = idx - 5 * 256 * 256;
  if (j < 5 * 128 * 256) {  // htT[i][n][k]
    int i = j >> 15, r = j & 32767, nn = r >> 8, k = r & 255;
    htT[j] = __float2bfloat16(htW[(i * 256 + k) * 128 + nn]);
    return;
  }
  int j2 = j - 5 * 128 * 256;
  if (j2 < 5 * 128 * 128) {  // inT[i][n][k]
    int i = j2 >> 14, r = j2 & 16383, nn = r >> 7, k = r & 127;
    inT[j2] = __float2bfloat16(inW[(i * 128 + k) * 128 + nn]);
  }
}

// Build initial x (bf16) = [tok_emb[input_node] | inputtext] ++ tok_emb1[linenode]
__global__ void build_x(const int* __restrict__ node, const int* __restrict__ text,
                        const int* __restrict__ line, const float* __restrict__ te,
                        const float* __restrict__ te1, __hip_bfloat16* __restrict__ xbf) {
  int idx = blockIdx.x * 256 + threadIdx.x;  // B*N*D = 2M exactly
  int d = idx & 127;
  int p = (idx >> 7) & 2047;
  int b = idx >> 18;
  float v;
  if (p < NLQ) {
    if (d < 127) {
      int id = node[b * NLQ + p];
      v = te[(size_t)id * 127 + d];
    } else {
      v = (float)text[b * NLQ + p];
    }
  } else {
    int id = line[b * NLQ + (p - NLQ)];
    v = te1[(size_t)id * 128 + d];
  }
  xbf[idx] = __float2bfloat16(v);
}

__device__ __forceinline__ float waveMax(float v) {
#pragma unroll
  for (int m = 32; m; m >>= 1) v = fmaxf(v, __shfl_xor(v, m, 64));
  return v;
}
__device__ __forceinline__ float waveSum(float v) {
#pragma unroll
  for (int m = 32; m; m >>= 1) v += __shfl_xor(v, m, 64);
  return v;
}

// logits = h[:, :NL] @ res2_W + b; mask; softmax; loss
__global__ __launch_bounds__(256) void final_k(const float* __restrict__ h,
                                               const float* __restrict__ w2,
                                               const float* __restrict__ b2,
                                               const int* __restrict__ node,
                                               const float* __restrict__ res,
                                               float* __restrict__ outLoss,
                                               float* __restrict__ outSm) {
  int b = blockIdx.x, t = threadIdx.x;
  __shared__ float lw[128];
  __shared__ float lg[NLQ];
  __shared__ float red[4];
  __shared__ float bc;
  if (t < 128) lw[t] = w2[t];
  __syncthreads();
  float bias = b2[0];
  for (int n = t; n < NLQ; n += 256) {
    const float* hr = h + ((size_t)b * NQ + n) * DQ;
    float s = 0.f;
#pragma unroll
    for (int d = 0; d < 128; d += 4) {
      float4 hv = *(const float4*)(hr + d);
      s += hv.x * lw[d] + hv.y * lw[d + 1] + hv.z * lw[d + 2] + hv.w * lw[d + 3];
    }
    lg[n] = (node[b * NLQ + n] == 2) ? (s + bias) : -1e9f;
  }
  __syncthreads();
  int lane = t & 63, w = t >> 6;
  float mx = -3.0e38f;
  for (int n = t; n < NLQ; n += 256) mx = fmaxf(mx, lg[n]);
  mx = waveMax(mx);
  if (lane == 0) red[w] = mx;
  __syncthreads();
  if (t == 0) bc = fmaxf(fmaxf(red[0], red[1]), fmaxf(red[2], red[3]));
  __syncthreads();
  float M = bc;
  float sum = 0.f;
  for (int n = t; n < NLQ; n += 256) {
    float e = expf(lg[n] - M);
    lg[n] = e;
    sum += e;
  }
  __syncthreads();
  sum = waveSum(sum);
  if (lane == 0) red[w] = sum;
  __syncthreads();
  if (t == 0) bc = red[0] + red[1] + red[2] + red[3];
  __syncthreads();
  float inv = 1.f / bc;
  float loss = 0.f;
  for (int n = t; n < NLQ; n += 256) {
    float sm = lg[n] * inv;
    outSm[b * NLQ + n] = sm;
    float c = fminf(fmaxf(sm, 1e-10f), 1.f);
    loss += -logf(c) * res[b * NLQ + n];
  }
  loss = waveSum(loss);
  __syncthreads();
  if (lane == 0) red[w] = loss;
  __syncthreads();
  if (t == 0) outLoss[b] = red[0] + red[1] + red[2] + red[3];
}

__global__ void copy_x(const float4* __restrict__ h, float4* __restrict__ out) {
  int idx = blockIdx.x * 256 + threadIdx.x;  // 8*1024*32 = 262144 exactly
  int r = idx >> 5;
  int c = idx & 31;
  int b = r >> 10, n = r & 1023;
  out[idx] = h[((size_t)b * NQ + n) * 32 + c];
}

__global__ void ws_fail(float* out) {
  if (threadIdx.x == 0) out[0] = -7.0e7f;  // sentinel: workspace too small
}

// ---------------------------------------------------------------------------
extern "C" void kernel_launch(void* const* d_in, const int* in_sizes, int n_in,
                              void* d_out, int out_size, void* d_ws, size_t ws_size,
                              hipStream_t stream) {
  const int* input_node = (const int*)d_in[0];
  const float* inputad  = (const float*)d_in[2];
  const float* res      = (const float*)d_in[3];
  const int* inputtext  = (const int*)d_in[4];
  const int* linenode   = (const int*)d_in[5];
  const float* tok_emb  = (const float*)d_in[8];
  const float* tok_emb1 = (const float*)d_in[9];
  const float* in_W  = (const float*)d_in[10];
  const float* in_b  = (const float*)d_in[11];
  const float* ug_W  = (const float*)d_in[12];
  const float* ug_b  = (const float*)d_in[13];
  const float* rg_W  = (const float*)d_in[14];
  const float* rg_b  = (const float*)d_in[15];
  const float* ht_W  = (const float*)d_in[16];
  const float* ht_b  = (const float*)d_in[17];
  const float* res2_W = (const float*)d_in[18];
  const float* res2_b = (const float*)d_in[19];

  char* ws = (char*)d_ws;
  const size_t OFF_ADJ = 0;
  const size_t OFF_H   = OFF_ADJ + (size_t)BQ * NQ * NQ * 2;   // adj bf16, 67 MB
  const size_t OFF_Z   = OFF_H   + (size_t)BQ * NQ * DQ * 4;   // h fp32
  const size_t OFF_HBF = OFF_Z   + (size_t)BQ * NQ * DQ * 4;   // z fp32
  const size_t OFF_HT  = OFF_HBF + (size_t)BQ * NQ * DQ * 2;   // h bf16 (row-major)
  const size_t OFF_MS  = OFF_HT  + (size_t)BQ * NQ * DQ * 2;   // h bf16 transposed [b][d][n]
  const size_t OFF_RH  = OFF_MS  + (size_t)BQ * NQ * DQ * 2;   // msgs bf16
  const size_t OFF_WZR = OFF_RH  + (size_t)BQ * NQ * DQ * 2;   // r*h bf16
  const size_t OFF_HTW = OFF_WZR + (size_t)5 * 256 * 256 * 2;
  const size_t OFF_INW = OFF_HTW + (size_t)5 * 128 * 256 * 2;
  const size_t NEED    = OFF_INW + (size_t)5 * 128 * 128 * 2;  // ~102 MB
  if (ws_size < NEED) {
    ws_fail<<<1, 64, 0, stream>>>((float*)d_out);
    return;
  }

  __hip_bfloat16* adjbf = (__hip_bfloat16*)(ws + OFF_ADJ);
  float* hF             = (float*)(ws + OFF_H);
  float* zF             = (float*)(ws + OFF_Z);
  __hip_bfloat16* hbf   = (__hip_bfloat16*)(ws + OFF_HBF);
  __hip_bfloat16* hT    = (__hip_bfloat16*)(ws + OFF_HT);
  __hip_bfloat16* msbf  = (__hip_bfloat16*)(ws + OFF_MS);
  __hip_bfloat16* rhbf  = (__hip_bfloat16*)(ws + OFF_RH);
  __hip_bfloat16* wzrT  = (__hip_bfloat16*)(ws + OFF_WZR);
  __hip_bfloat16* htT   = (__hip_bfloat16*)(ws + OFF_HTW);
  __hip_bfloat16* inT   = (__hip_bfloat16*)(ws + OFF_INW);

  float* outLoss = (float*)d_out;
  float* outSm = outLoss + BQ;
  float* outX = outSm + BQ * NLQ;

  cvt_adj<<<4096, 256, 0, stream>>>((const float4*)inputad, (ushort4*)adjbf,
                                    (int)((size_t)BQ * NQ * NQ / 4));
  pack_weights<<<2240, 256, 0, stream>>>(ug_W, rg_W, ht_W, in_W, wzrT, htT, inT);
  build_x<<<8192, 256, 0, stream>>>(input_node, inputtext, linenode, tok_emb, tok_emb1, hbf);

  for (int i = 0; i < 5; ++i) {
    // h = x @ in_W[i] + in_b[i]  (in-place on hbf: each block only reads its own rows)
    gemm_bf16<3><<<dim3(256, 1, 1), 256, 0, stream>>>(
        hbf, nullptr, inT + i * 128 * 128, 128, 1 << 30, 128, 128, 0, 0, 16384,
        in_b + i * 128, nullptr, hF, nullptr, hbf, hT);
    for (int s = 0; s < 3; ++s) {
      // msgs = adj @ h  (B = hT, per batch)
      gemm_bf16<0><<<dim3(32, 1, 8), 256, 0, stream>>>(
          adjbf, nullptr, hT, 2048, 1 << 30, 2048, 2048,
          (size_t)NQ * NQ, (size_t)DQ * NQ, 2048,
          nullptr, nullptr, nullptr, nullptr, msbf, nullptr);
      // z = sigmoid([h|msgs]@ug), rh = sigmoid([h|msgs]@rg) * h
      gemm_bf16<1><<<dim3(256, 2, 1), 256, 0, stream>>>(
          hbf, msbf, wzrT + i * 256 * 256, 128, 128, 256, 256, 0, 0, 16384,
          ug_b + i * 128, rg_b + i * 128, hF, zF, rhbf, nullptr);
      // h = z*h + (1-z)*tanh([rh|msgs]@ht)
      gemm_bf16<2><<<dim3(256, 1, 1), 256, 0, stream>>>(
          rhbf, msbf, htT + i * 128 * 256, 128, 128, 256, 256, 0, 0, 16384,
          ht_b + i * 128, nullptr, hF, zF, hbf, hT);
    }
  }

  final_k<<<8, 256, 0, stream>>>(hF, res2_W, res2_b, input_node, res, outLoss, outSm);
  copy_x<<<1024, 256, 0, stream>>>((const float4*)hF, (float4*)outX);
}

// Round 2
// 729.233 us; speedup vs baseline: 1.4546x; 1.4546x over previous
//
#include <hip/hip_runtime.h>
#include <hip/hip_bf16.h>

// Problem constants
#define BQ   8
#define NLQ  1024
#define NQ   2048
#define DQ   128

typedef __attribute__((ext_vector_type(4))) float f32x4;
typedef __attribute__((ext_vector_type(8))) short bf16x8;

__device__ __forceinline__ unsigned short bfbits(float f) {
  __hip_bfloat16 h = __float2bfloat16(f);
  return __builtin_bit_cast(unsigned short, h);
}
__device__ __forceinline__ float sigm(float x) { return 1.f / (1.f + expf(-x)); }

// async global->LDS, 16B per lane. LDS dest is wave-uniform base + lane*16.
__device__ __forceinline__ void g2l16(const void* g, void* l) {
  __builtin_amdgcn_global_load_lds(
      (__attribute__((address_space(1))) void*)(uintptr_t)g,
      (__attribute__((address_space(3))) void*)(uint32_t)(uintptr_t)l,
      16, 0, 0);
}

// ---------------------------------------------------------------------------
// Pipelined bf16 MFMA GEMM: C(M x Ncols) = A(M x K, row-major; optionally
// split into two buffers at k=ksplit) * BT(Ncols x K, row-major)^T
// Tile: 64 (M) x 128 (N), BK=64, 4 waves (2x2), wave tile 32x64.
// 3-buffer LDS pipeline, 2-deep prefetch, counted vmcnt(6), raw barriers.
// T2 XOR swizzle: global source col pre-swizzled, ds_read XORs (row&7)<<3.
// EPI: 0=msgs(bf16 out), 1=z/r+rh, 2=ht+GRU update, 3=in-proj
// ---------------------------------------------------------------------------
template <int EPI>
__global__ __launch_bounds__(256) void gemm_bf16(
    const __hip_bfloat16* __restrict__ A0, const __hip_bfloat16* __restrict__ A1,
    const __hip_bfloat16* __restrict__ BT,
    int ldA, int ksplit, int ldBT, int K,
    size_t aBatchStride, size_t btBatchStride, int rowsPerBatch,
    const float* __restrict__ bias0, const float* __restrict__ bias1,
    float* __restrict__ hF, float* __restrict__ zF,
    __hip_bfloat16* __restrict__ bf0, __hip_bfloat16* __restrict__ bf1) {
  __shared__ __align__(16) __hip_bfloat16 As[3][64 * 64];
  __shared__ __align__(16) __hip_bfloat16 Bs[3][128 * 64];
  const int t = threadIdx.x;
  const int lane = t & 63;
  const int w = t >> 6;
  const int wr = w >> 1, wc = w & 1;
  const int bm = blockIdx.x, bn = blockIdx.y, bz = blockIdx.z;

  const __hip_bfloat16* aB0 = A0 + (size_t)bz * aBatchStride + (size_t)bm * 64 * ldA;
  const __hip_bfloat16* aB1 = A1 ? (A1 + (size_t)bm * 64 * ldA) : (const __hip_bfloat16*)0;
  const __hip_bfloat16* btB = BT + (size_t)bz * btBatchStride + (size_t)bn * 128 * ldBT;

  f32x4 acc[2][4] = {};

  const int srA = w * 16 + (lane >> 3);            // + q*8
  const int srB = w * 32 + (lane >> 3);            // + q*8
  const int swzCol = ((lane & 7) ^ (lane >> 3)) << 3;  // pre-swizzled source col
  const int lr = lane & 15, lh = lane >> 4;
  const int rswz = (lr & 7) << 3;                  // ds_read element-index XOR

  const int nt = K >> 6;  // number of BK=64 steps (always >= 2 here)

  auto stage = [&](int bi, int k0) {
    const __hip_bfloat16* aSrc = (k0 < ksplit) ? aB0 : aB1;
    const int kl = (k0 < ksplit) ? k0 : (k0 - ksplit);
#pragma unroll
    for (int q = 0; q < 2; ++q)
      g2l16(aSrc + (size_t)(srA + q * 8) * ldA + kl + swzCol,
            (char*)As[bi] + w * 2048 + q * 1024);
#pragma unroll
    for (int q = 0; q < 4; ++q)
      g2l16(btB + (size_t)(srB + q * 8) * ldBT + k0 + swzCol,
            (char*)Bs[bi] + w * 4096 + q * 1024);
  };

  stage(0, 0);
  stage(1, 64);
  asm volatile("s_waitcnt vmcnt(6)" ::: "memory");  // stage 0 complete
  __builtin_amdgcn_s_barrier();

  int cur = 0;
  for (int tt = 0; tt < nt; ++tt) {
    // fragment loads from LDS (swizzled)
    bf16x8 av[2][2], bv[2][4];
#pragma unroll
    for (int kk2 = 0; kk2 < 2; ++kk2) {
#pragma unroll
      for (int m = 0; m < 2; ++m)
        av[kk2][m] = *(const bf16x8*)&As[cur][(wr * 32 + m * 16 + lr) * 64 +
                                             ((kk2 * 32 + lh * 8) ^ rswz)];
#pragma unroll
      for (int n = 0; n < 4; ++n)
        bv[kk2][n] = *(const bf16x8*)&Bs[cur][(wc * 64 + n * 16 + lr) * 64 +
                                              ((kk2 * 32 + lh * 8) ^ rswz)];
    }
    // issue next-next stage while reads are in flight
    if (tt + 2 < nt) {
      int bi = cur + 2; if (bi >= 3) bi -= 3;
      stage(bi, (tt + 2) << 6);
    }
    __builtin_amdgcn_s_setprio(1);
#pragma unroll
    for (int kk2 = 0; kk2 < 2; ++kk2)
#pragma unroll
      for (int m = 0; m < 2; ++m)
#pragma unroll
        for (int n = 0; n < 4; ++n)
          acc[m][n] = __builtin_amdgcn_mfma_f32_16x16x32_bf16(av[kk2][m], bv[kk2][n],
                                                              acc[m][n], 0, 0, 0);
    __builtin_amdgcn_s_setprio(0);
    if (tt < nt - 2) {
      asm volatile("s_waitcnt vmcnt(6)" ::: "memory");  // stage tt+1 complete
      __builtin_amdgcn_s_barrier();
    } else if (tt == nt - 2) {
      asm volatile("s_waitcnt vmcnt(0)" ::: "memory");
      __builtin_amdgcn_s_barrier();
    }
    ++cur; if (cur == 3) cur = 0;
  }

  // Epilogue. C/D layout: col = lane&15, row = (lane>>4)*4 + reg.
#pragma unroll
  for (int m = 0; m < 2; ++m) {
    const int row0 = bm * 64 + wr * 32 + m * 16 + lh * 4;
    const int gRow = bz * rowsPerBatch + row0;
#pragma unroll
    for (int n = 0; n < 4; ++n) {
      const int col = bn * 128 + wc * 64 + n * 16 + lr;
      f32x4 v = acc[m][n];
      if constexpr (EPI == 0) {  // msgs -> bf16
#pragma unroll
        for (int r = 0; r < 4; ++r)
          bf0[(size_t)(gRow + r) * DQ + col] = __float2bfloat16(v[r]);
      } else if constexpr (EPI == 1) {  // z (cols<128) / r -> r*h (cols>=128)
        if (col < 128) {               // block-uniform branch (bn==0)
          const float bb = bias0[col];
#pragma unroll
          for (int r = 0; r < 4; ++r)
            zF[(size_t)(gRow + r) * DQ + col] = sigm(v[r] + bb);
        } else {
          const int c = col - 128;
          const float bb = bias1[c];
#pragma unroll
          for (int r = 0; r < 4; ++r) {
            size_t idx = (size_t)(gRow + r) * DQ + c;
            float rr = sigm(v[r] + bb);
            bf0[idx] = __float2bfloat16(rr * hF[idx]);
          }
        }
      } else {  // EPI 2 (ht + GRU update) and EPI 3 (in-proj)
        const float bb = bias0[col];
        ushort4 us;
        unsigned short* up = (unsigned short*)&us;
#pragma unroll
        for (int r = 0; r < 4; ++r) {
          size_t idx = (size_t)(gRow + r) * DQ + col;
          float hn;
          if constexpr (EPI == 2) {
            float tv = tanhf(v[r] + bb);
            float zv = zF[idx];
            float hv = hF[idx];
            hn = zv * hv + (1.f - zv) * tv;
          } else {
            hn = v[r] + bb;
          }
          hF[idx] = hn;
          bf0[idx] = __float2bfloat16(hn);
          up[r] = bfbits(hn);
        }
        // transposed bf16 write: hT[b][d][n], 4 consecutive n -> one 8B store
        const int bb_ = gRow >> 11;
        const int nl = gRow & 2047;
        *(ushort4*)((char*)bf1 + ((size_t)bb_ * (DQ * NQ) + (size_t)col * NQ + nl) * 2) = us;
      }
    }
  }
}

// ---------------------------------------------------------------------------
__global__ void cvt_adj(const float4* __restrict__ in, ushort4* __restrict__ out, int n4) {
  int stride = gridDim.x * blockDim.x;
  for (int i = blockIdx.x * blockDim.x + threadIdx.x; i < n4; i += stride) {
    float4 v = in[i];
    ushort4 o;
    o.x = bfbits(v.x); o.y = bfbits(v.y); o.z = bfbits(v.z); o.w = bfbits(v.w);
    out[i] = o;
  }
}

// Pack weights to bf16, transposed to N x K row-major.
__global__ void pack_weights(const float* __restrict__ ugW, const float* __restrict__ rgW,
                             const float* __restrict__ htW, const float* __restrict__ inW,
                             __hip_bfloat16* __restrict__ wzrT, __hip_bfloat16* __restrict__ htT,
                             __hip_bfloat16* __restrict__ inT) {
  int idx = blockIdx.x * 256 + threadIdx.x;
  if (idx < 5 * 256 * 256) {  // wzrT[i][n][k], n<128 -> ug, else rg
    int i = idx >> 16, r = idx & 65535, nn = r >> 8, k = r & 255;
    float v = (nn < 128) ? ugW[(i * 256 + k) * 128 + nn] : rgW[(i * 256 + k) * 128 + nn - 128];
    wzrT[idx] = __float2bfloat16(v);
    return;
  }
  int j = idx - 5 * 256 * 256;
  if (j < 5 * 128 * 256) {  // htT[i][n][k]
    int i = j >> 15, r = j & 32767, nn = r >> 8, k = r & 255;
    htT[j] = __float2bfloat16(htW[(i * 256 + k) * 128 + nn]);
    return;
  }
  int j2 = j - 5 * 128 * 256;
  if (j2 < 5 * 128 * 128) {  // inT[i][n][k]
    int i = j2 >> 14, r = j2 & 16383, nn = r >> 7, k = r & 127;
    inT[j2] = __float2bfloat16(inW[(i * 128 + k) * 128 + nn]);
  }
}

// Build initial x (bf16) = [tok_emb[input_node] | inputtext] ++ tok_emb1[linenode]
__global__ void build_x(const int* __restrict__ node, const int* __restrict__ text,
                        const int* __restrict__ line, const float* __restrict__ te,
                        const float* __restrict__ te1, __hip_bfloat16* __restrict__ xbf) {
  int idx = blockIdx.x * 256 + threadIdx.x;  // B*N*D = 2M exactly
  int d = idx & 127;
  int p = (idx >> 7) & 2047;
  int b = idx >> 18;
  float v;
  if (p < NLQ) {
    if (d < 127) {
      int id = node[b * NLQ + p];
      v = te[(size_t)id * 127 + d];
    } else {
      v = (float)text[b * NLQ + p];
    }
  } else {
    int id = line[b * NLQ + (p - NLQ)];
    v = te1[(size_t)id * 128 + d];
  }
  xbf[idx] = __float2bfloat16(v);
}

__device__ __forceinline__ float waveMax(float v) {
#pragma unroll
  for (int m = 32; m; m >>= 1) v = fmaxf(v, __shfl_xor(v, m, 64));
  return v;
}
__device__ __forceinline__ float waveSum(float v) {
#pragma unroll
  for (int m = 32; m; m >>= 1) v += __shfl_xor(v, m, 64);
  return v;
}

// logits = h[:, :NL] @ res2_W + b; mask; softmax; loss
__global__ __launch_bounds__(256) void final_k(const float* __restrict__ h,
                                               const float* __restrict__ w2,
                                               const float* __restrict__ b2,
                                               const int* __restrict__ node,
                                               const float* __restrict__ res,
                                               float* __restrict__ outLoss,
                                               float* __restrict__ outSm) {
  int b = blockIdx.x, t = threadIdx.x;
  __shared__ float lw[128];
  __shared__ float lg[NLQ];
  __shared__ float red[4];
  __shared__ float bc;
  if (t < 128) lw[t] = w2[t];
  __syncthreads();
  float bias = b2[0];
  for (int n = t; n < NLQ; n += 256) {
    const float* hr = h + ((size_t)b * NQ + n) * DQ;
    float s = 0.f;
#pragma unroll
    for (int d = 0; d < 128; d += 4) {
      float4 hv = *(const float4*)(hr + d);
      s += hv.x * lw[d] + hv.y * lw[d + 1] + hv.z * lw[d + 2] + hv.w * lw[d + 3];
    }
    lg[n] = (node[b * NLQ + n] == 2) ? (s + bias) : -1e9f;
  }
  __syncthreads();
  int lane = t & 63, w = t >> 6;
  float mx = -3.0e38f;
  for (int n = t; n < NLQ; n += 256) mx = fmaxf(mx, lg[n]);
  mx = waveMax(mx);
  if (lane == 0) red[w] = mx;
  __syncthreads();
  if (t == 0) bc = fmaxf(fmaxf(red[0], red[1]), fmaxf(red[2], red[3]));
  __syncthreads();
  float M = bc;
  float sum = 0.f;
  for (int n = t; n < NLQ; n += 256) {
    float e = expf(lg[n] - M);
    lg[n] = e;
    sum += e;
  }
  __syncthreads();
  sum = waveSum(sum);
  if (lane == 0) red[w] = sum;
  __syncthreads();
  if (t == 0) bc = red[0] + red[1] + red[2] + red[3];
  __syncthreads();
  float inv = 1.f / bc;
  float loss = 0.f;
  for (int n = t; n < NLQ; n += 256) {
    float sm = lg[n] * inv;
    outSm[b * NLQ + n] = sm;
    float c = fminf(fmaxf(sm, 1e-10f), 1.f);
    loss += -logf(c) * res[b * NLQ + n];
  }
  loss = waveSum(loss);
  __syncthreads();
  if (lane == 0) red[w] = loss;
  __syncthreads();
  if (t == 0) outLoss[b] = red[0] + red[1] + red[2] + red[3];
}

__global__ void copy_x(const float4* __restrict__ h, float4* __restrict__ out) {
  int idx = blockIdx.x * 256 + threadIdx.x;  // 8*1024*32 = 262144 exactly
  int r = idx >> 5;
  int c = idx & 31;
  int b = r >> 10, n = r & 1023;
  out[idx] = h[((size_t)b * NQ + n) * 32 + c];
}

__global__ void ws_fail(float* out) {
  if (threadIdx.x == 0) out[0] = -7.0e7f;  // sentinel: workspace too small
}

// ---------------------------------------------------------------------------
extern "C" void kernel_launch(void* const* d_in, const int* in_sizes, int n_in,
                              void* d_out, int out_size, void* d_ws, size_t ws_size,
                              hipStream_t stream) {
  const int* input_node = (const int*)d_in[0];
  const float* inputad  = (const float*)d_in[2];
  const float* res      = (const float*)d_in[3];
  const int* inputtext  = (const int*)d_in[4];
  const int* linenode   = (const int*)d_in[5];
  const float* tok_emb  = (const float*)d_in[8];
  const float* tok_emb1 = (const float*)d_in[9];
  const float* in_W  = (const float*)d_in[10];
  const float* in_b  = (const float*)d_in[11];
  const float* ug_W  = (const float*)d_in[12];
  const float* ug_b  = (const float*)d_in[13];
  const float* rg_W  = (const float*)d_in[14];
  const float* rg_b  = (const float*)d_in[15];
  const float* ht_W  = (const float*)d_in[16];
  const float* ht_b  = (const float*)d_in[17];
  const float* res2_W = (const float*)d_in[18];
  const float* res2_b = (const float*)d_in[19];

  char* ws = (char*)d_ws;
  const size_t OFF_ADJ = 0;
  const size_t OFF_H   = OFF_ADJ + (size_t)BQ * NQ * NQ * 2;   // adj bf16, 67 MB
  const size_t OFF_Z   = OFF_H   + (size_t)BQ * NQ * DQ * 4;   // h fp32
  const size_t OFF_HBF = OFF_Z   + (size_t)BQ * NQ * DQ * 4;   // z fp32
  const size_t OFF_HT  = OFF_HBF + (size_t)BQ * NQ * DQ * 2;   // h bf16 (row-major)
  const size_t OFF_MS  = OFF_HT  + (size_t)BQ * NQ * DQ * 2;   // h bf16 transposed [b][d][n]
  const size_t OFF_RH  = OFF_MS  + (size_t)BQ * NQ * DQ * 2;   // msgs bf16
  const size_t OFF_WZR = OFF_RH  + (size_t)BQ * NQ * DQ * 2;   // r*h bf16
  const size_t OFF_HTW = OFF_WZR + (size_t)5 * 256 * 256 * 2;
  const size_t OFF_INW = OFF_HTW + (size_t)5 * 128 * 256 * 2;
  const size_t NEED    = OFF_INW + (size_t)5 * 128 * 128 * 2;  // ~102 MB
  if (ws_size < NEED) {
    ws_fail<<<1, 64, 0, stream>>>((float*)d_out);
    return;
  }

  __hip_bfloat16* adjbf = (__hip_bfloat16*)(ws + OFF_ADJ);
  float* hF             = (float*)(ws + OFF_H);
  float* zF             = (float*)(ws + OFF_Z);
  __hip_bfloat16* hbf   = (__hip_bfloat16*)(ws + OFF_HBF);
  __hip_bfloat16* hT    = (__hip_bfloat16*)(ws + OFF_HT);
  __hip_bfloat16* msbf  = (__hip_bfloat16*)(ws + OFF_MS);
  __hip_bfloat16* rhbf  = (__hip_bfloat16*)(ws + OFF_RH);
  __hip_bfloat16* wzrT  = (__hip_bfloat16*)(ws + OFF_WZR);
  __hip_bfloat16* htT   = (__hip_bfloat16*)(ws + OFF_HTW);
  __hip_bfloat16* inT   = (__hip_bfloat16*)(ws + OFF_INW);

  float* outLoss = (float*)d_out;
  float* outSm = outLoss + BQ;
  float* outX = outSm + BQ * NLQ;

  cvt_adj<<<4096, 256, 0, stream>>>((const float4*)inputad, (ushort4*)adjbf,
                                    (int)((size_t)BQ * NQ * NQ / 4));
  pack_weights<<<2240, 256, 0, stream>>>(ug_W, rg_W, ht_W, in_W, wzrT, htT, inT);
  build_x<<<8192, 256, 0, stream>>>(input_node, inputtext, linenode, tok_emb, tok_emb1, hbf);

  for (int i = 0; i < 5; ++i) {
    // h = x @ in_W[i] + in_b[i]  (in-place on hbf: each block only reads its own rows)
    gemm_bf16<3><<<dim3(256, 1, 1), 256, 0, stream>>>(
        hbf, nullptr, inT + i * 128 * 128, 128, 1 << 30, 128, 128, 0, 0, 16384,
        in_b + i * 128, nullptr, hF, nullptr, hbf, hT);
    for (int s = 0; s < 3; ++s) {
      // msgs = adj @ h  (B = hT, per batch)
      gemm_bf16<0><<<dim3(32, 1, 8), 256, 0, stream>>>(
          adjbf, nullptr, hT, 2048, 1 << 30, 2048, 2048,
          (size_t)NQ * NQ, (size_t)DQ * NQ, 2048,
          nullptr, nullptr, nullptr, nullptr, msbf, nullptr);
      // z = sigmoid([h|msgs]@ug), rh = sigmoid([h|msgs]@rg) * h
      gemm_bf16<1><<<dim3(256, 2, 1), 256, 0, stream>>>(
          hbf, msbf, wzrT + i * 256 * 256, 128, 128, 256, 256, 0, 0, 16384,
          ug_b + i * 128, rg_b + i * 128, hF, zF, rhbf, nullptr);
      // h = z*h + (1-z)*tanh([rh|msgs]@ht)
      gemm_bf16<2><<<dim3(256, 1, 1), 256, 0, stream>>>(
          rhbf, msbf, htT + i * 128 * 256, 128, 128, 256, 256, 0, 0, 16384,
          ht_b + i * 128, nullptr, hF, zF, hbf, hT);
    }
  }

  final_k<<<8, 256, 0, stream>>>(hF, res2_W, res2_b, input_node, res, outLoss, outSm);
  copy_x<<<1024, 256, 0, stream>>>((const float4*)hF, (float4*)outX);
}